// Round 2
// baseline (5061.983 us; speedup 1.0000x reference)
//
#include <hip/hip_runtime.h>
#include <cstdint>
#include <cstddef>

#define B_SZ 32
#define NPTS 16384
#define NSAMP 2048
#define F_IN 64
#define C_IN 67
#define D_OUT 128
#define FPS_THREADS 1024
#define PPT 16                  // points per thread
#define PAIRS (PPT / 2)

typedef float f32x2 __attribute__((ext_vector_type(2)));

// ---------------------------------------------------------------------------
// FPS: one block per batch, 1024 threads, 16 points/thread in registers.
// Block argmax via per-wave butterfly + lane0 atomicMax on a packed u64 key
// (dist_bits<<32 | ~idx): max key == max dist, tie -> lowest index, exactly
// matching jnp.argmax first-occurrence semantics (dist >= 0 so f32 bits are
// order-preserving). New centroid is broadcast from the WINNER's registers
// (no global load on the critical path).
// ---------------------------------------------------------------------------
__global__ __launch_bounds__(FPS_THREADS, 4)
void fps_kernel(const float* __restrict__ xyz,       // [B, N, 3]
                const int* __restrict__ init_far,    // [B]
                int* __restrict__ idx_out,           // [B, S]
                float* __restrict__ newxyz_out)      // [B, S, 3]
{
#pragma clang fp contract(off)
    const int b = blockIdx.x;
    const int tid = threadIdx.x;
    const float* base = xyz + (size_t)b * NPTS * 3;

    // load 16 points/thread as 8 float2 pairs; pair k = global points
    // (tid + 2k*1024, tid + (2k+1)*1024)  -> index increases with k, then .y
    f32x2 px[PAIRS], py[PAIRS], pz[PAIRS], dist[PAIRS];
#pragma unroll
    for (int k = 0; k < PAIRS; ++k) {
        const int i0 = tid + (2 * k) * FPS_THREADS;
        const int i1 = i0 + FPS_THREADS;
        px[k] = f32x2{base[i0 * 3 + 0], base[i1 * 3 + 0]};
        py[k] = f32x2{base[i0 * 3 + 1], base[i1 * 3 + 1]};
        pz[k] = f32x2{base[i0 * 3 + 2], base[i1 * 3 + 2]};
        dist[k] = f32x2{1e10f, 1e10f};
    }

    __shared__ unsigned long long s_key[2];
    __shared__ float s_cx, s_cy, s_cz;

    if (tid == 0) { s_key[0] = 0ull; s_key[1] = 0ull; }

    // initial centroid: uniform broadcast load, once
    const int f0 = init_far[b];
    int cur = f0;
    float cx = base[f0 * 3 + 0];
    float cy = base[f0 * 3 + 1];
    float cz = base[f0 * 3 + 2];
    __syncthreads();

    const int lane = tid & 63;

    for (int s = 0; s < NSAMP; ++s) {
        // record BEFORE update (reference scan semantics); reset the other
        // key slot (its readers finished before the previous barrier)
        if (tid == 0) {
            idx_out[b * NSAMP + s] = cur;
            float* o = newxyz_out + (size_t)(b * NSAMP + s) * 3;
            o[0] = cx; o[1] = cy; o[2] = cz;
            s_key[(s + 1) & 1] = 0ull;
        }

        const f32x2 cx2 = {cx, cx}, cy2 = {cy, cy}, cz2 = {cz, cz};
        float best = -1.0f;
        int   bi   = 0;
#pragma unroll
        for (int k = 0; k < PAIRS; ++k) {
            const f32x2 dx = px[k] - cx2;
            const f32x2 dy = py[k] - cy2;
            const f32x2 dz = pz[k] - cz2;
            const f32x2 d  = (dx * dx + dy * dy) + dz * dz;   // contract OFF
            const float nd0 = fminf(dist[k].x, d.x);
            const float nd1 = fminf(dist[k].y, d.y);
            dist[k].x = nd0;
            dist[k].y = nd1;
            // increasing global index order + strict '>' => lowest index on tie
            if (nd0 > best) { best = nd0; bi = tid + (2 * k) * FPS_THREADS; }
            if (nd1 > best) { best = nd1; bi = tid + (2 * k + 1) * FPS_THREADS; }
        }

        // 64-lane butterfly argmax, tie -> lower index
#pragma unroll
        for (int off = 32; off >= 1; off >>= 1) {
            const float ov = __shfl_xor(best, off, 64);
            const int   oi = __shfl_xor(bi, off, 64);
            if (ov > best || (ov == best && oi < bi)) { best = ov; bi = oi; }
        }
        if (lane == 0) {
            const unsigned long long key =
                ((unsigned long long)__float_as_uint(best) << 32) |
                (unsigned long long)(~(unsigned)bi);
            atomicMax(&s_key[s & 1], key);
        }
        __syncthreads();

        const unsigned long long key = s_key[s & 1];
        const int vi = (int)(~(unsigned)(key & 0xFFFFFFFFull));
        cur = vi;

        // winner broadcasts the new centroid from its registers
        if ((vi & (FPS_THREADS - 1)) == tid) {
            const int wp = vi >> 10;              // point slot 0..15
            float ox = px[0].x, oy = py[0].x, oz = pz[0].x;
#pragma unroll
            for (int p = 1; p < PPT; ++p) {
                const int  k = p >> 1;
                const bool m = (wp == p);
                if (p & 1) {
                    ox = m ? px[k].y : ox; oy = m ? py[k].y : oy; oz = m ? pz[k].y : oz;
                } else {
                    ox = m ? px[k].x : ox; oy = m ? py[k].x : oy; oz = m ? pz[k].x : oz;
                }
            }
            s_cx = ox; s_cy = oy; s_cz = oz;
        }
        __syncthreads();
        cx = s_cx; cy = s_cy; cz = s_cz;
    }
}

// ---------------------------------------------------------------------------
// Kernel 2: gather selected rows, 1x1 conv (x @ W + b), ReLU.
// ---------------------------------------------------------------------------
#define SAMP_PER_BLK 16

__global__ __launch_bounds__(256)
void gather_linear_relu_kernel(const float* __restrict__ xyz,    // [B,N,3]
                               const float* __restrict__ feats,  // [B,N,F]
                               const int* __restrict__ idx,      // [B*S]
                               const float* __restrict__ W,      // [67,128]
                               const float* __restrict__ bias,   // [128]
                               float* __restrict__ out)          // [B*S,128]
{
    __shared__ float sW[C_IN][D_OUT];
    __shared__ float sX[SAMP_PER_BLK][C_IN + 1];
    __shared__ float sB[D_OUT];

    const int tid = threadIdx.x;

    for (int i = tid; i < C_IN * D_OUT; i += 256)
        (&sW[0][0])[i] = W[i];
    if (tid < D_OUT) sB[tid] = bias[tid];

    const int gs0 = blockIdx.x * SAMP_PER_BLK;

    {
        const int si = tid >> 4;
        const int j  = tid & 15;
        const int gs = gs0 + si;
        const int bb = gs >> 11;
        const int pt = idx[gs];
        const float* frow = feats + ((size_t)bb * NPTS + pt) * F_IN;
        const float* xrow = xyz   + ((size_t)bb * NPTS + pt) * 3;
        for (int c = j; c < F_IN; c += 16) sX[si][c] = frow[c];
        if (j < 3) sX[si][F_IN + j] = xrow[j];
    }
    __syncthreads();

    const int d = tid & 127;
    const int g = tid >> 7;
    float acc[8];
#pragma unroll
    for (int k = 0; k < 8; ++k) acc[k] = 0.0f;

    for (int c = 0; c < C_IN; ++c) {
        const float w = sW[c][d];
#pragma unroll
        for (int k = 0; k < 8; ++k)
            acc[k] = fmaf(sX[g * 8 + k][c], w, acc[k]);
    }

    const float bv = sB[d];
#pragma unroll
    for (int k = 0; k < 8; ++k) {
        const int gs = gs0 + g * 8 + k;
        const float v = acc[k] + bv;
        out[(size_t)gs * D_OUT + d] = fmaxf(v, 0.0f);
    }
}

// ---------------------------------------------------------------------------
extern "C" void kernel_launch(void* const* d_in, const int* in_sizes, int n_in,
                              void* d_out, int out_size, void* d_ws, size_t ws_size,
                              hipStream_t stream) {
    const float* xyz      = (const float*)d_in[0];
    const float* feats    = (const float*)d_in[1];
    const int*   init_far = (const int*)d_in[2];
    const float* W        = (const float*)d_in[3];
    const float* bias     = (const float*)d_in[4];

    float* out_newxyz = (float*)d_out;
    float* out_conv   = (float*)d_out + (size_t)B_SZ * NSAMP * 3;
    int*   idx_ws     = (int*)d_ws;

    fps_kernel<<<B_SZ, FPS_THREADS, 0, stream>>>(xyz, init_far, idx_ws, out_newxyz);

    const int nblocks = (B_SZ * NSAMP) / SAMP_PER_BLK;
    gather_linear_relu_kernel<<<nblocks, 256, 0, stream>>>(
        xyz, feats, idx_ws, W, bias, out_conv);
}